// Round 12
// baseline (58742.798 us; speedup 1.0000x reference)
//
#include <hip/hip_runtime.h>

#define T_LEN 512
#define D_DIM 32
#define N_DIM 64
#define B_ALL 128
#define NTHR 512   // 8 waves/block; wave = 1 batch row; 2 blocks/CU -> 4 w/SIMD

__device__ __forceinline__ float rcp_f(float x) {
#if __has_builtin(__builtin_amdgcn_rcpf)
    return __builtin_amdgcn_rcpf(x);
#else
    return 1.0f / x;
#endif
}
__device__ __forceinline__ float tanh_f(float x) {
    float e = __expf(2.0f * x);
    return 1.0f - 2.0f * rcp_f(e + 1.0f);
}
__device__ __forceinline__ float sig_f(float x) {
    return rcp_f(1.0f + __expf(-x));
}
__device__ __forceinline__ float rl(float v, int L) {
    return __int_as_float(__builtin_amdgcn_readlane(__float_as_int(v), L));
}

// Wave-local recurrence; occupancy raised to 4 waves/SIMD (r11 stalled at 2:
// wall 6904 cyc/CU-iter vs VALU 3330 + LDS 3650 -> ~3200 cyc unhidden latency).
// Wave = 1 row; 4096 waves = 4/SIMD exactly. W split k=0..47 in 192 pinned
// scalar regs (pins once per 2 t-steps), k=48..63 from LDS (keeps LDS pipe at
// 256 b128/CU-iter, same as r11, despite 2x waves). No barrier in the t-loop.
__global__ void __launch_bounds__(NTHR, 4)
imv_lstm_scan(const float* __restrict__ x,
              const float* __restrict__ Uj, const float* __restrict__ Ui,
              const float* __restrict__ Uf, const float* __restrict__ Uo,
              const float* __restrict__ Wj, const float* __restrict__ Wi,
              const float* __restrict__ Wf, const float* __restrict__ Wo,
              const float* __restrict__ bj, const float* __restrict__ bi_,
              const float* __restrict__ bf_, const float* __restrict__ bo,
              const float* __restrict__ Fa, const float* __restrict__ Fab,
              const float* __restrict__ Fbw, const float* __restrict__ Fbb,
              const float* __restrict__ Pw, const float* __restrict__ Pb,
              float* __restrict__ wmu, float* __restrict__ wbeta)
{
    __shared__ float4 sW[N_DIM * N_DIM];   // 64 KB, [k*64 + n] = {j,i,f,o}

    const int tid  = threadIdx.x;
    const int d    = blockIdx.x & 31;
    const int bt   = blockIdx.x >> 5;      // 0..15
    const int wv   = tid >> 6;             // 0..7
    const int lane = tid & 63;             // = n
    const int row  = bt * 8 + wv;          // this wave's batch row

    for (int i = tid; i < N_DIM * N_DIM; i += NTHR) {
        int off = d * (N_DIM * N_DIM) + i;
        sW[i] = make_float4(Wj[off], Wi[off], Wf[off], Wo[off]);
    }
    __syncthreads();   // the only barrier

    const int dn = d * N_DIM + lane;
    const float u_j = Uj[dn], u_i = Ui[dn], u_f = Uf[dn], u_o = Uo[dn];
    const float cbj = bj[dn], cbi = bi_[dn], cbf = bf_[dn], cbo = bo[dn];
    const float far = Fa[dn];
    const float fab = Fab[d];

    const float* xp = x + (size_t)row * T_LEN * D_DIM + d;
    const float4* wp = sW + lane;

    // ---- k = 0..47 into 192 named scalar registers, loaded once ----
#define WDECL(K) float w##K##0, w##K##1, w##K##2, w##K##3;
#define WLOAD(K) { float4 t_ = wp[(K) * 64]; \
                   w##K##0 = t_.x; w##K##1 = t_.y; w##K##2 = t_.z; w##K##3 = t_.w; }
    WDECL(0)  WDECL(1)  WDECL(2)  WDECL(3)  WDECL(4)  WDECL(5)  WDECL(6)  WDECL(7)
    WDECL(8)  WDECL(9)  WDECL(10) WDECL(11) WDECL(12) WDECL(13) WDECL(14) WDECL(15)
    WDECL(16) WDECL(17) WDECL(18) WDECL(19) WDECL(20) WDECL(21) WDECL(22) WDECL(23)
    WDECL(24) WDECL(25) WDECL(26) WDECL(27) WDECL(28) WDECL(29) WDECL(30) WDECL(31)
    WDECL(32) WDECL(33) WDECL(34) WDECL(35) WDECL(36) WDECL(37) WDECL(38) WDECL(39)
    WDECL(40) WDECL(41) WDECL(42) WDECL(43) WDECL(44) WDECL(45) WDECL(46) WDECL(47)
    WLOAD(0)  WLOAD(1)  WLOAD(2)  WLOAD(3)  WLOAD(4)  WLOAD(5)  WLOAD(6)  WLOAD(7)
    WLOAD(8)  WLOAD(9)  WLOAD(10) WLOAD(11) WLOAD(12) WLOAD(13) WLOAD(14) WLOAD(15)
    WLOAD(16) WLOAD(17) WLOAD(18) WLOAD(19) WLOAD(20) WLOAD(21) WLOAD(22) WLOAD(23)
    WLOAD(24) WLOAD(25) WLOAD(26) WLOAD(27) WLOAD(28) WLOAD(29) WLOAD(30) WLOAD(31)
    WLOAD(32) WLOAD(33) WLOAD(34) WLOAD(35) WLOAD(36) WLOAD(37) WLOAD(38) WLOAD(39)
    WLOAD(40) WLOAD(41) WLOAD(42) WLOAD(43) WLOAD(44) WLOAD(45) WLOAD(46) WLOAD(47)
#undef WDECL
#undef WLOAD

    float h = 0.f, c = 0.f, ga = 0.f, as = 0.f;

#define RFMA(K, A) { \
        float q_ = rl(h, K); \
        A.x = fmaf(q_, w##K##0, A.x); A.y = fmaf(q_, w##K##1, A.y); \
        A.z = fmaf(q_, w##K##2, A.z); A.w = fmaf(q_, w##K##3, A.w); }

    auto lstm_step = [&](int t) {
        float xv = xp[(size_t)t * D_DIM];
        float4 a = {0.f, 0.f, 0.f, 0.f};
        RFMA(0,a)  RFMA(1,a)  RFMA(2,a)  RFMA(3,a)  RFMA(4,a)  RFMA(5,a)
        RFMA(6,a)  RFMA(7,a)  RFMA(8,a)  RFMA(9,a)  RFMA(10,a) RFMA(11,a)
        RFMA(12,a) RFMA(13,a) RFMA(14,a) RFMA(15,a) RFMA(16,a) RFMA(17,a)
        RFMA(18,a) RFMA(19,a) RFMA(20,a) RFMA(21,a) RFMA(22,a) RFMA(23,a)
        RFMA(24,a) RFMA(25,a) RFMA(26,a) RFMA(27,a) RFMA(28,a) RFMA(29,a)
        RFMA(30,a) RFMA(31,a) RFMA(32,a) RFMA(33,a) RFMA(34,a) RFMA(35,a)
        RFMA(36,a) RFMA(37,a) RFMA(38,a) RFMA(39,a) RFMA(40,a) RFMA(41,a)
        RFMA(42,a) RFMA(43,a) RFMA(44,a) RFMA(45,a) RFMA(46,a) RFMA(47,a)

        // k = 48..63 from LDS (16 b128; constant-index array, SROA-promoted)
        float4 wl[16];
        #pragma unroll
        for (int u = 0; u < 16; ++u)
            wl[u] = wp[(48 + u) * 64];
        #pragma unroll
        for (int u = 0; u < 16; ++u) {
            float q_ = rl(h, 48 + u);
            a.x = fmaf(q_, wl[u].x, a.x); a.y = fmaf(q_, wl[u].y, a.y);
            a.z = fmaf(q_, wl[u].z, a.z); a.w = fmaf(q_, wl[u].w, a.w);
        }

        // gates + state + online alpha (in-wave)
        float jp = a.x + fmaf(xv, u_j, cbj);
        float ip = a.y + fmaf(xv, u_i, cbi);
        float fp = a.z + fmaf(xv, u_f, cbf);
        float op = a.w + fmaf(xv, u_o, cbo);
        c = fmaf(c, sig_f(fp), sig_f(ip) * tanh_f(jp));
        h = sig_f(op) * tanh_f(c);
        float ps = h * far;
        ps += __shfl_xor(ps, 1);  ps += __shfl_xor(ps, 2);
        ps += __shfl_xor(ps, 4);  ps += __shfl_xor(ps, 8);
        ps += __shfl_xor(ps, 16); ps += __shfl_xor(ps, 32);
        float al = __expf(tanh_f(ps + fab));
        as += al; ga = fmaf(al, h, ga);
    };

#define PIN4(K) "+v"(w##K##0), "+v"(w##K##1), "+v"(w##K##2), "+v"(w##K##3)

    #pragma unroll 1
    for (int t = 0; t < T_LEN; t += 2) {
        // pin W scalars once per 2 steps: no remat/sinking possible
        asm volatile("" : PIN4(0),  PIN4(1),  PIN4(2),  PIN4(3));
        asm volatile("" : PIN4(4),  PIN4(5),  PIN4(6),  PIN4(7));
        asm volatile("" : PIN4(8),  PIN4(9),  PIN4(10), PIN4(11));
        asm volatile("" : PIN4(12), PIN4(13), PIN4(14), PIN4(15));
        asm volatile("" : PIN4(16), PIN4(17), PIN4(18), PIN4(19));
        asm volatile("" : PIN4(20), PIN4(21), PIN4(22), PIN4(23));
        asm volatile("" : PIN4(24), PIN4(25), PIN4(26), PIN4(27));
        asm volatile("" : PIN4(28), PIN4(29), PIN4(30), PIN4(31));
        asm volatile("" : PIN4(32), PIN4(33), PIN4(34), PIN4(35));
        asm volatile("" : PIN4(36), PIN4(37), PIN4(38), PIN4(39));
        asm volatile("" : PIN4(40), PIN4(41), PIN4(42), PIN4(43));
        asm volatile("" : PIN4(44), PIN4(45), PIN4(46), PIN4(47));

        lstm_step(t);
        lstm_step(t + 1);
    }
#undef PIN4
#undef RFMA

    // ---- epilogue: this row's mu, beta ----
    const float pwa = Pw[lane],  pwb = Pw[64 + lane];
    const float fwa = Fbw[lane], fwb = Fbw[64 + lane];
    float gn = ga * rcp_f(as);
    float pm = fmaf(gn, pwa, h * pwb);
    float pv = fmaf(gn, fwa, h * fwb);
    pm += __shfl_xor(pm, 1);  pm += __shfl_xor(pm, 2);
    pm += __shfl_xor(pm, 4);  pm += __shfl_xor(pm, 8);
    pm += __shfl_xor(pm, 16); pm += __shfl_xor(pm, 32);
    pv += __shfl_xor(pv, 1);  pv += __shfl_xor(pv, 2);
    pv += __shfl_xor(pv, 4);  pv += __shfl_xor(pv, 8);
    pv += __shfl_xor(pv, 16); pv += __shfl_xor(pv, 32);
    if (lane == 0) {
        wmu  [row * D_DIM + d] = pm + Pb[0];
        wbeta[row * D_DIM + d] = __expf(tanh_f(pv + Fbb[0]));
    }
}

// beta softmax over d + weighted sum -> out[b]
__global__ void imv_finalize(const float* __restrict__ wmu,
                             const float* __restrict__ wbeta,
                             float* __restrict__ out)
{
    int b = blockIdx.x * 64 + threadIdx.x;
    if (b >= B_ALL) return;
    float s1 = 0.f, s2 = 0.f;
    for (int d = 0; d < D_DIM; ++d) {
        float be = wbeta[b * D_DIM + d];
        s1 = fmaf(be, wmu[b * D_DIM + d], s1);
        s2 += be;
    }
    out[b] = s1 / s2;
}

extern "C" void kernel_launch(void* const* d_in, const int* in_sizes, int n_in,
                              void* d_out, int out_size, void* d_ws, size_t ws_size,
                              hipStream_t stream)
{
    const float* x   = (const float*)d_in[0];
    const float* U_j = (const float*)d_in[1];
    const float* U_i = (const float*)d_in[2];
    const float* U_f = (const float*)d_in[3];
    const float* U_o = (const float*)d_in[4];
    const float* W_j = (const float*)d_in[5];
    const float* W_i = (const float*)d_in[6];
    const float* W_f = (const float*)d_in[7];
    const float* W_o = (const float*)d_in[8];
    const float* b_j = (const float*)d_in[9];
    const float* b_i = (const float*)d_in[10];
    const float* b_f = (const float*)d_in[11];
    const float* b_o = (const float*)d_in[12];
    const float* Fan  = (const float*)d_in[13];
    const float* Fanb = (const float*)d_in[14];
    const float* Fbw  = (const float*)d_in[15];
    const float* Fbb  = (const float*)d_in[16];
    const float* Phw  = (const float*)d_in[17];
    const float* Phb  = (const float*)d_in[18];

    float* wmu   = (float*)d_ws;
    float* wbeta = wmu + B_ALL * D_DIM;

    imv_lstm_scan<<<dim3(512), dim3(NTHR), 0, stream>>>(
        x, U_j, U_i, U_f, U_o, W_j, W_i, W_f, W_o,
        b_j, b_i, b_f, b_o, Fan, Fanb, Fbw, Fbb, Phw, Phb,
        wmu, wbeta);

    imv_finalize<<<dim3(2), dim3(64), 0, stream>>>(wmu, wbeta, (float*)d_out);
}

// Round 13
// 1360.962 us; speedup vs baseline: 43.1627x; 43.1627x over previous
//
#include <hip/hip_runtime.h>

#define T_LEN 512
#define D_DIM 32
#define N_DIM 64
#define B_ALL 128
#define NTHR 256   // 4 waves/block; wave = 2 batch rows; 2 blocks/CU

typedef float v2 __attribute__((ext_vector_type(2)));

__device__ __forceinline__ float rcp_f(float x) {
#if __has_builtin(__builtin_amdgcn_rcpf)
    return __builtin_amdgcn_rcpf(x);
#else
    return 1.0f / x;
#endif
}
__device__ __forceinline__ float tanh_f(float x) {
    float e = __expf(2.0f * x);
    return 1.0f - 2.0f * rcp_f(e + 1.0f);
}
__device__ __forceinline__ float sig_f(float x) {
    return rcp_f(1.0f + __expf(-x));
}
__device__ __forceinline__ float rl(float v, int L) {
    return __int_as_float(__builtin_amdgcn_readlane(__float_as_int(v), L));
}

// r11 structure (wave-local recurrence, 2 rows/wave, 2 waves/SIMD, W split
// 128-reg/128-LDS, no t-loop barrier) + PACKED FP32 FMA: W held as float2
// gate-pairs {j,i},{f,o}; __builtin_elementwise_fma on float2 lowers to
// v_pk_fma_f32 -> matmul 512 fma -> 256 pk_fma per wave-iter. Pins are
// "+v"(float2) = 64-bit tied register operands (r10's failure was the
// 128-bit float4 operand, which clang demoted to indirect).
// r12 lesson: 2 waves/SIMD <=> 256 VGPR budget is the occupancy frontier.
__global__ void __launch_bounds__(NTHR, 2)
imv_lstm_scan(const float* __restrict__ x,
              const float* __restrict__ Uj, const float* __restrict__ Ui,
              const float* __restrict__ Uf, const float* __restrict__ Uo,
              const float* __restrict__ Wj, const float* __restrict__ Wi,
              const float* __restrict__ Wf, const float* __restrict__ Wo,
              const float* __restrict__ bj, const float* __restrict__ bi_,
              const float* __restrict__ bf_, const float* __restrict__ bo,
              const float* __restrict__ Fa, const float* __restrict__ Fab,
              const float* __restrict__ Fbw, const float* __restrict__ Fbb,
              const float* __restrict__ Pw, const float* __restrict__ Pb,
              float* __restrict__ wmu, float* __restrict__ wbeta)
{
    __shared__ float4 sW[N_DIM * N_DIM];   // 64 KB, [k*64 + n] = {j,i,f,o}

    const int tid  = threadIdx.x;
    const int d    = blockIdx.x & 31;
    const int bt   = blockIdx.x >> 5;      // 0..15
    const int wv   = tid >> 6;
    const int lane = tid & 63;             // = n
    const int row0 = bt * 8 + wv * 2;      // this wave's two batch rows

    for (int i = tid; i < N_DIM * N_DIM; i += NTHR) {
        int off = d * (N_DIM * N_DIM) + i;
        sW[i] = make_float4(Wj[off], Wi[off], Wf[off], Wo[off]);
    }
    __syncthreads();   // the only barrier

    const int dn = d * N_DIM + lane;
    const float u_j = Uj[dn], u_i = Ui[dn], u_f = Uf[dn], u_o = Uo[dn];
    const float cbj = bj[dn], cbi = bi_[dn], cbf = bf_[dn], cbo = bo[dn];
    const float far = Fa[dn];
    const float fab = Fab[d];

    const float* xp0 = x + (size_t)(row0 + 0) * T_LEN * D_DIM + d;
    const float* xp1 = x + (size_t)(row0 + 1) * T_LEN * D_DIM + d;

    const float4* wp = sW + lane;

    // ---- k = 0..31 as 64 named float2 gate-pairs (128 VGPR), loaded once ----
#define WDECL(K) v2 wji##K, wfo##K;
#define WLOAD(K) { float4 t_ = wp[(K) * 64]; \
                   wji##K = (v2){t_.x, t_.y}; wfo##K = (v2){t_.z, t_.w}; }
    WDECL(0)  WDECL(1)  WDECL(2)  WDECL(3)  WDECL(4)  WDECL(5)  WDECL(6)  WDECL(7)
    WDECL(8)  WDECL(9)  WDECL(10) WDECL(11) WDECL(12) WDECL(13) WDECL(14) WDECL(15)
    WDECL(16) WDECL(17) WDECL(18) WDECL(19) WDECL(20) WDECL(21) WDECL(22) WDECL(23)
    WDECL(24) WDECL(25) WDECL(26) WDECL(27) WDECL(28) WDECL(29) WDECL(30) WDECL(31)
    WLOAD(0)  WLOAD(1)  WLOAD(2)  WLOAD(3)  WLOAD(4)  WLOAD(5)  WLOAD(6)  WLOAD(7)
    WLOAD(8)  WLOAD(9)  WLOAD(10) WLOAD(11) WLOAD(12) WLOAD(13) WLOAD(14) WLOAD(15)
    WLOAD(16) WLOAD(17) WLOAD(18) WLOAD(19) WLOAD(20) WLOAD(21) WLOAD(22) WLOAD(23)
    WLOAD(24) WLOAD(25) WLOAD(26) WLOAD(27) WLOAD(28) WLOAD(29) WLOAD(30) WLOAD(31)
#undef WDECL
#undef WLOAD

    float h0 = 0.f, h1 = 0.f, c0 = 0.f, c1 = 0.f;
    float ga0 = 0.f, ga1 = 0.f, as0 = 0.f, as1 = 0.f;
    float xc0 = xp0[0], xc1 = xp1[0];

#define PIN2(K) "+v"(wji##K), "+v"(wfo##K)

    #pragma unroll 1
    for (int t = 0; t < T_LEN; ++t) {
        // pin W pairs: asm "rewrites" them -> no remat/sinking possible
        asm volatile("" : PIN2(0),  PIN2(1),  PIN2(2),  PIN2(3));
        asm volatile("" : PIN2(4),  PIN2(5),  PIN2(6),  PIN2(7));
        asm volatile("" : PIN2(8),  PIN2(9),  PIN2(10), PIN2(11));
        asm volatile("" : PIN2(12), PIN2(13), PIN2(14), PIN2(15));
        asm volatile("" : PIN2(16), PIN2(17), PIN2(18), PIN2(19));
        asm volatile("" : PIN2(20), PIN2(21), PIN2(22), PIN2(23));
        asm volatile("" : PIN2(24), PIN2(25), PIN2(26), PIN2(27));
        asm volatile("" : PIN2(28), PIN2(29), PIN2(30), PIN2(31));

        float xn0 = 0.f, xn1 = 0.f;
        if (t + 1 < T_LEN) {
            xn0 = xp0[(size_t)(t + 1) * D_DIM];
            xn1 = xp1[(size_t)(t + 1) * D_DIM];
        }

        v2 aji0 = {0.f, 0.f}, afo0 = {0.f, 0.f};
        v2 aji1 = {0.f, 0.f}, afo1 = {0.f, 0.f};

        // ---- k = 0..31 from registers (packed: 4 pk_fma per k) ----
#define RFMA(K) { \
        float q0 = rl(h0, K); \
        float q1 = rl(h1, K); \
        v2 q0v = {q0, q0}, q1v = {q1, q1}; \
        aji0 = __builtin_elementwise_fma(q0v, wji##K, aji0); \
        afo0 = __builtin_elementwise_fma(q0v, wfo##K, afo0); \
        aji1 = __builtin_elementwise_fma(q1v, wji##K, aji1); \
        afo1 = __builtin_elementwise_fma(q1v, wfo##K, afo1); }
        RFMA(0)  RFMA(1)  RFMA(2)  RFMA(3)  RFMA(4)  RFMA(5)  RFMA(6)  RFMA(7)
        RFMA(8)  RFMA(9)  RFMA(10) RFMA(11) RFMA(12) RFMA(13) RFMA(14) RFMA(15)
        RFMA(16) RFMA(17) RFMA(18) RFMA(19) RFMA(20) RFMA(21) RFMA(22) RFMA(23)
        RFMA(24) RFMA(25) RFMA(26) RFMA(27) RFMA(28) RFMA(29) RFMA(30) RFMA(31)
#undef RFMA

        // ---- k = 32..63 from LDS, 4 chunks of 8 (32 VGPR in flight) ----
        #pragma unroll 1
        for (int kc = 4; kc < 8; ++kc) {
            float4 w[8];
            #pragma unroll
            for (int u = 0; u < 8; ++u)
                w[u] = wp[(kc * 8 + u) * 64];
            #pragma unroll
            for (int u = 0; u < 8; ++u) {
                const int k = kc * 8 + u;        // uniform -> SGPR readlane
                float q0 = rl(h0, k);
                float q1 = rl(h1, k);
                v2 q0v = {q0, q0}, q1v = {q1, q1};
                v2 lji = {w[u].x, w[u].y};
                v2 lfo = {w[u].z, w[u].w};
                aji0 = __builtin_elementwise_fma(q0v, lji, aji0);
                afo0 = __builtin_elementwise_fma(q0v, lfo, afo0);
                aji1 = __builtin_elementwise_fma(q1v, lji, aji1);
                afo1 = __builtin_elementwise_fma(q1v, lfo, afo1);
            }
        }

        // ---- gates + state + online alpha (in-wave) ----
#define ROW_STEP(AJI, AFO, XC, H, C, GA, AS) { \
        float jp = AJI.x + fmaf(XC, u_j, cbj); \
        float ip = AJI.y + fmaf(XC, u_i, cbi); \
        float fp = AFO.x + fmaf(XC, u_f, cbf); \
        float op = AFO.y + fmaf(XC, u_o, cbo); \
        C = fmaf(C, sig_f(fp), sig_f(ip) * tanh_f(jp)); \
        H = sig_f(op) * tanh_f(C); \
        float ps = H * far; \
        ps += __shfl_xor(ps, 1);  ps += __shfl_xor(ps, 2); \
        ps += __shfl_xor(ps, 4);  ps += __shfl_xor(ps, 8); \
        ps += __shfl_xor(ps, 16); ps += __shfl_xor(ps, 32); \
        float al = __expf(tanh_f(ps + fab)); \
        AS += al; GA = fmaf(al, H, GA); }

        ROW_STEP(aji0, afo0, xc0, h0, c0, ga0, as0)
        ROW_STEP(aji1, afo1, xc1, h1, c1, ga1, as1)
#undef ROW_STEP

        xc0 = xn0; xc1 = xn1;
    }
#undef PIN2

    // ---- epilogue ----
    const float pwa = Pw[lane],  pwb = Pw[64 + lane];
    const float fwa = Fbw[lane], fwb = Fbw[64 + lane];
    const float pb0 = Pb[0], fb0 = Fbb[0];

#define ROW_OUT(J, H, GA, AS) { \
        float gn = GA * rcp_f(AS); \
        float pm = fmaf(gn, pwa, H * pwb); \
        float pv = fmaf(gn, fwa, H * fwb); \
        pm += __shfl_xor(pm, 1);  pm += __shfl_xor(pm, 2); \
        pm += __shfl_xor(pm, 4);  pm += __shfl_xor(pm, 8); \
        pm += __shfl_xor(pm, 16); pm += __shfl_xor(pm, 32); \
        pv += __shfl_xor(pv, 1);  pv += __shfl_xor(pv, 2); \
        pv += __shfl_xor(pv, 4);  pv += __shfl_xor(pv, 8); \
        pv += __shfl_xor(pv, 16); pv += __shfl_xor(pv, 32); \
        if (lane == 0) { \
            wmu  [(row0 + (J)) * D_DIM + d] = pm + pb0; \
            wbeta[(row0 + (J)) * D_DIM + d] = __expf(tanh_f(pv + fb0)); } }

    ROW_OUT(0, h0, ga0, as0)
    ROW_OUT(1, h1, ga1, as1)
#undef ROW_OUT
}

// beta softmax over d + weighted sum -> out[b]
__global__ void imv_finalize(const float* __restrict__ wmu,
                             const float* __restrict__ wbeta,
                             float* __restrict__ out)
{
    int b = blockIdx.x * 64 + threadIdx.x;
    if (b >= B_ALL) return;
    float s1 = 0.f, s2 = 0.f;
    for (int d = 0; d < D_DIM; ++d) {
        float be = wbeta[b * D_DIM + d];
        s1 = fmaf(be, wmu[b * D_DIM + d], s1);
        s2 += be;
    }
    out[b] = s1 / s2;
}

extern "C" void kernel_launch(void* const* d_in, const int* in_sizes, int n_in,
                              void* d_out, int out_size, void* d_ws, size_t ws_size,
                              hipStream_t stream)
{
    const float* x   = (const float*)d_in[0];
    const float* U_j = (const float*)d_in[1];
    const float* U_i = (const float*)d_in[2];
    const float* U_f = (const float*)d_in[3];
    const float* U_o = (const float*)d_in[4];
    const float* W_j = (const float*)d_in[5];
    const float* W_i = (const float*)d_in[6];
    const float* W_f = (const float*)d_in[7];
    const float* W_o = (const float*)d_in[8];
    const float* b_j = (const float*)d_in[9];
    const float* b_i = (const float*)d_in[10];
    const float* b_f = (const float*)d_in[11];
    const float* b_o = (const float*)d_in[12];
    const float* Fan  = (const float*)d_in[13];
    const float* Fanb = (const float*)d_in[14];
    const float* Fbw  = (const float*)d_in[15];
    const float* Fbb  = (const float*)d_in[16];
    const float* Phw  = (const float*)d_in[17];
    const float* Phb  = (const float*)d_in[18];

    float* wmu   = (float*)d_ws;
    float* wbeta = wmu + B_ALL * D_DIM;

    imv_lstm_scan<<<dim3(512), dim3(NTHR), 0, stream>>>(
        x, U_j, U_i, U_f, U_o, W_j, W_i, W_f, W_o,
        b_j, b_i, b_f, b_o, Fan, Fanb, Fbw, Fbb, Phw, Phb,
        wmu, wbeta);

    imv_finalize<<<dim3(2), dim3(64), 0, stream>>>(wmu, wbeta, (float*)d_out);
}

// Round 14
// 948.837 us; speedup vs baseline: 61.9103x; 1.4343x over previous
//
#include <hip/hip_runtime.h>

#define T_LEN 512
#define D_DIM 32
#define N_DIM 64
#define B_ALL 128
#define R_TILE 8      // rows per block
#define HSTRIDE 68    // sH32 row stride (uints): 16B-aligned, bank-spread

typedef short s8v __attribute__((ext_vector_type(8)));   // 8 bf16 (4 VGPRs)
typedef float f4v __attribute__((ext_vector_type(4)));   // MFMA C/D
typedef unsigned int uint;
typedef unsigned short ushort;

__device__ __forceinline__ float rcp_f(float x) {
#if __has_builtin(__builtin_amdgcn_rcpf)
    return __builtin_amdgcn_rcpf(x);
#else
    return 1.0f / x;
#endif
}
__device__ __forceinline__ float tanh_f(float x) {
    float e = __expf(2.0f * x);
    return 1.0f - 2.0f * rcp_f(e + 1.0f);
}
__device__ __forceinline__ float sig_f(float x) {
    return rcp_f(1.0f + __expf(-x));
}
__device__ __forceinline__ uint f2bf(float f) {   // fp32 -> bf16 bits, RNE
    uint u = __float_as_uint(f);
    return (u + 0x7FFFu + ((u >> 16) & 1u)) >> 16;
}
__device__ __forceinline__ s8v pack4(uint a, uint b, uint c, uint d_) {
    union { uint u[4]; s8v v; } x;
    x.u[0] = a; x.u[1] = b; x.u[2] = c; x.u[3] = d_;
    return x.v;
}

// Block = (d, 8-row tile): grid 32*16 = 512, 256 thr (4 waves), 2 blocks/CU.
// Recurrent matmul on MATRIX CORES: mfma_f32_16x16x32_bf16 with hi/lo split
// (h = hh+hl, W = Wh+Wl; 3 terms AhBh+AlBh+AhBl; fp32 C). Wave w owns
// n in [16w,16w+16): its 4 gate C-tiles -> gate combine is lane-local.
// W frags in registers (built once). h round-trips LDS packed hi|lo per u32.
// Alpha (softmax over t) reduced across waves via tiny LDS + 2 barriers/step.
// A-frag layout: A[m=lane&15][k=quad*8+j]; B[k=quad*8+j][n=lane&15];
// C: col=lane&15 (n), row=quad*4+reg (rows 0..7 real, 8..15 ignored).
__global__ void __launch_bounds__(256, 2)
imv_lstm_scan(const float* __restrict__ x,
              const float* __restrict__ Uj, const float* __restrict__ Ui,
              const float* __restrict__ Uf, const float* __restrict__ Uo,
              const float* __restrict__ Wj, const float* __restrict__ Wi,
              const float* __restrict__ Wf, const float* __restrict__ Wo,
              const float* __restrict__ bj, const float* __restrict__ bi_,
              const float* __restrict__ bf_, const float* __restrict__ bo,
              const float* __restrict__ Fa, const float* __restrict__ Fab,
              const float* __restrict__ Fbw, const float* __restrict__ Fbb,
              const float* __restrict__ Pw, const float* __restrict__ Pb,
              float* __restrict__ wmu, float* __restrict__ wbeta)
{
    __shared__ float sXT[T_LEN][R_TILE];     // 16 KB, [t][r]
    __shared__ uint  sH32[16][HSTRIDE];      // 4.3 KB, h packed hi|lo
    __shared__ float sPS[8][4];              // alpha partials [row][wave]
    __shared__ float sPV[8][4];              // epilogue second buffer

    const int tid  = threadIdx.x;
    const int lane = tid & 63;
    const int wv   = tid >> 6;               // 0..3
    const int quad = lane >> 4;              // 0..3
    const int col  = lane & 15;
    const int d    = blockIdx.x & 31;
    const int rt   = blockIdx.x >> 5;        // 0..15
    const int r0   = rt * R_TILE;
    const int n    = wv * 16 + col;          // this lane's n for C/B/state

    // ---- stage x transposed: sXT[t][r] ----
    for (int i = tid; i < R_TILE * T_LEN; i += 256) {
        int t = i >> 3, r = i & 7;
        sXT[t][r] = x[((size_t)(r0 + r) * T_LEN + t) * D_DIM + d];
    }
    for (int i = tid; i < 16 * HSTRIDE; i += 256)
        ((uint*)sH32)[i] = 0u;               // h0 = 0 (rows 8-15 stay 0)

    // ---- W fragments into registers: Bh/Bl[gate][k-chunk] ----
    s8v Bh[4][2], Bl[4][2];
    #pragma unroll
    for (int g = 0; g < 4; ++g) {
        const float* Wg = (g == 0 ? Wj : g == 1 ? Wi : g == 2 ? Wf : Wo)
                          + d * (N_DIM * N_DIM);
        #pragma unroll
        for (int c = 0; c < 2; ++c) {
            uint hp[4], lp[4];
            #pragma unroll
            for (int jp = 0; jp < 4; ++jp) {
                float w0 = Wg[(32 * c + quad * 8 + 2 * jp + 0) * N_DIM + n];
                float w1 = Wg[(32 * c + quad * 8 + 2 * jp + 1) * N_DIM + n];
                uint u0 = __float_as_uint(w0), u1 = __float_as_uint(w1);
                uint h0b = u0 & 0xFFFF0000u, h1b = u1 & 0xFFFF0000u;
                float l0 = w0 - __uint_as_float(h0b);
                float l1 = w1 - __uint_as_float(h1b);
                hp[jp] = (u0 >> 16) | h1b;
                lp[jp] = f2bf(l0) | (f2bf(l1) << 16);
            }
            Bh[g][c] = pack4(hp[0], hp[1], hp[2], hp[3]);
            Bl[g][c] = pack4(lp[0], lp[1], lp[2], lp[3]);
        }
    }

    const int dn = d * N_DIM + n;
    const float u_j = Uj[dn], u_i = Ui[dn], u_f = Uf[dn], u_o = Uo[dn];
    const float cbj = bj[dn], cbi = bi_[dn], cbf = bf_[dn], cbo = bo[dn];
    const float fan = Fa[dn];
    const float fab = Fab[d];

    __syncthreads();

    float c_[4] = {0.f, 0.f, 0.f, 0.f};
    float h_[4] = {0.f, 0.f, 0.f, 0.f};
    float ga[4] = {0.f, 0.f, 0.f, 0.f};
    float as[4] = {0.f, 0.f, 0.f, 0.f};

    #pragma unroll 1
    for (int t = 0; t < T_LEN; ++t) {
        // ---- A fragments from packed h (hi|lo in each u32) ----
        s8v Ah[2], Al[2];
        #pragma unroll
        for (int c = 0; c < 2; ++c) {
            const uint* hp = &sH32[col][32 * c + quad * 8];
            uint4 wa = *(const uint4*)hp;
            uint4 wb = *(const uint4*)(hp + 4);
            Ah[c] = pack4((wa.x >> 16) | (wa.y & 0xFFFF0000u),
                          (wa.z >> 16) | (wa.w & 0xFFFF0000u),
                          (wb.x >> 16) | (wb.y & 0xFFFF0000u),
                          (wb.z >> 16) | (wb.w & 0xFFFF0000u));
            Al[c] = pack4((wa.x & 0xFFFFu) | (wa.y << 16),
                          (wa.z & 0xFFFFu) | (wa.w << 16),
                          (wb.x & 0xFFFFu) | (wb.y << 16),
                          (wb.z & 0xFFFFu) | (wb.w << 16));
        }

        // ---- 24 MFMAs: 4 gates x 2 k-chunks x 3 hi/lo terms ----
        f4v acc[4];
        #pragma unroll
        for (int g = 0; g < 4; ++g) {
            f4v a = {0.f, 0.f, 0.f, 0.f};
            #pragma unroll
            for (int c = 0; c < 2; ++c) {
                a = __builtin_amdgcn_mfma_f32_16x16x32_bf16(Ah[c], Bh[g][c], a, 0, 0, 0);
                a = __builtin_amdgcn_mfma_f32_16x16x32_bf16(Al[c], Bh[g][c], a, 0, 0, 0);
                a = __builtin_amdgcn_mfma_f32_16x16x32_bf16(Ah[c], Bl[g][c], a, 0, 0, 0);
            }
            acc[g] = a;
        }

        // ---- stage 3 (rows quad*4+reg; quads 2-3 compute garbage, unused) ----
        f4v xr = *(const f4v*)&sXT[t][quad * 4 < 8 ? quad * 4 : 4];
        float ps[4];
        #pragma unroll
        for (int reg = 0; reg < 4; ++reg) {
            float xv = xr[reg];
            float jp = acc[0][reg] + fmaf(xv, u_j, cbj);
            float ip = acc[1][reg] + fmaf(xv, u_i, cbi);
            float fp = acc[2][reg] + fmaf(xv, u_f, cbf);
            float op = acc[3][reg] + fmaf(xv, u_o, cbo);
            c_[reg] = fmaf(c_[reg], sig_f(fp), sig_f(ip) * tanh_f(jp));
            h_[reg] = sig_f(op) * tanh_f(c_[reg]);
            ps[reg] = h_[reg] * fan;
        }
        // reduce ps over this wave's 16 n (masks <16 stay in quad-group)
        #pragma unroll
        for (int reg = 0; reg < 4; ++reg) {
            ps[reg] += __shfl_xor(ps[reg], 1);
            ps[reg] += __shfl_xor(ps[reg], 2);
            ps[reg] += __shfl_xor(ps[reg], 4);
            ps[reg] += __shfl_xor(ps[reg], 8);
        }

        __syncthreads();   // B1: all A-reads done before h overwrite

        if (quad < 2) {
            #pragma unroll
            for (int reg = 0; reg < 4; ++reg) {
                float hv = h_[reg];
                uint hb = __float_as_uint(hv) & 0xFFFF0000u;
                float lo = hv - __uint_as_float(hb);
                sH32[quad * 4 + reg][n] = hb | f2bf(lo);
            }
            if (col == 0) {
                #pragma unroll
                for (int reg = 0; reg < 4; ++reg)
                    sPS[quad * 4 + reg][wv] = ps[reg];
            }
        }

        __syncthreads();   // B2: h_t and alpha partials visible

        #pragma unroll
        for (int reg = 0; reg < 4; ++reg) {
            int r = (quad & 1) * 4 + reg;          // clamp to valid rows
            f4v tv = *(const f4v*)&sPS[r][0];
            float tot = tv[0] + tv[1] + tv[2] + tv[3];
            float al = __expf(tanh_f(tot + fab));
            as[reg] += al;
            ga[reg] = fmaf(al, h_[reg], ga[reg]);
        }
    }

    // ---- epilogue: mu, beta per (row, d) ----
    const float pwa = Pw[n],  pwb = Pw[64 + n];
    const float fwa = Fbw[n], fwb = Fbw[64 + n];
    float pm[4], pv[4];
    #pragma unroll
    for (int reg = 0; reg < 4; ++reg) {
        float gn = ga[reg] * rcp_f(as[reg]);
        pm[reg] = fmaf(gn, pwa, h_[reg] * pwb);
        pv[reg] = fmaf(gn, fwa, h_[reg] * fwb);
        pm[reg] += __shfl_xor(pm[reg], 1); pm[reg] += __shfl_xor(pm[reg], 2);
        pm[reg] += __shfl_xor(pm[reg], 4); pm[reg] += __shfl_xor(pm[reg], 8);
        pv[reg] += __shfl_xor(pv[reg], 1); pv[reg] += __shfl_xor(pv[reg], 2);
        pv[reg] += __shfl_xor(pv[reg], 4); pv[reg] += __shfl_xor(pv[reg], 8);
    }
    __syncthreads();   // last in-loop sPS reads are done
    if (quad < 2 && col == 0) {
        #pragma unroll
        for (int reg = 0; reg < 4; ++reg) {
            sPS[quad * 4 + reg][wv] = pm[reg];
            sPV[quad * 4 + reg][wv] = pv[reg];
        }
    }
    __syncthreads();
    if (tid < 8) {
        int r = tid;
        f4v a = *(const f4v*)&sPS[r][0];
        f4v b2 = *(const f4v*)&sPV[r][0];
        float mu = a[0] + a[1] + a[2] + a[3] + Pb[0];
        float bt = __expf(tanh_f(b2[0] + b2[1] + b2[2] + b2[3] + Fbb[0]));
        wmu  [(r0 + r) * D_DIM + d] = mu;
        wbeta[(r0 + r) * D_DIM + d] = bt;
    }
}

// beta softmax over d + weighted sum -> out[b]
__global__ void imv_finalize(const float* __restrict__ wmu,
                             const float* __restrict__ wbeta,
                             float* __restrict__ out)
{
    int b = blockIdx.x * 64 + threadIdx.x;
    if (b >= B_ALL) return;
    float s1 = 0.f, s2 = 0.f;
    for (int d = 0; d < D_DIM; ++d) {
        float be = wbeta[b * D_DIM + d];
        s1 = fmaf(be, wmu[b * D_DIM + d], s1);
        s2 += be;
    }
    out[b] = s1 / s2;
}

extern "C" void kernel_launch(void* const* d_in, const int* in_sizes, int n_in,
                              void* d_out, int out_size, void* d_ws, size_t ws_size,
                              hipStream_t stream)
{
    const float* x   = (const float*)d_in[0];
    const float* U_j = (const float*)d_in[1];
    const float* U_i = (const float*)d_in[2];
    const float* U_f = (const float*)d_in[3];
    const float* U_o = (const float*)d_in[4];
    const float* W_j = (const float*)d_in[5];
    const float* W_i = (const float*)d_in[6];
    const float* W_f = (const float*)d_in[7];
    const float* W_o = (const float*)d_in[8];
    const float* b_j = (const float*)d_in[9];
    const float* b_i = (const float*)d_in[10];
    const float* b_f = (const float*)d_in[11];
    const float* b_o = (const float*)d_in[12];
    const float* Fan  = (const float*)d_in[13];
    const float* Fanb = (const float*)d_in[14];
    const float* Fbw  = (const float*)d_in[15];
    const float* Fbb  = (const float*)d_in[16];
    const float* Phw  = (const float*)d_in[17];
    const float* Phb  = (const float*)d_in[18];

    float* wmu   = (float*)d_ws;
    float* wbeta = wmu + B_ALL * D_DIM;

    imv_lstm_scan<<<dim3(512), dim3(256), 0, stream>>>(
        x, U_j, U_i, U_f, U_o, W_j, W_i, W_f, W_o,
        b_j, b_i, b_f, b_o, Fan, Fanb, Fbw, Fbb, Phw, Phb,
        wmu, wbeta);

    imv_finalize<<<dim3(2), dim3(64), 0, stream>>>(wmu, wbeta, (float*)d_out);
}

// Round 15
// 697.602 us; speedup vs baseline: 84.2067x; 1.3601x over previous
//
#include <hip/hip_runtime.h>

#define T_LEN 512
#define D_DIM 32
#define N_DIM 64
#define B_ALL 128
#define R_TILE 16     // rows per block == full MFMA M dimension (no waste)
#define HSTRIDE 68    // sH32 row stride (uints): 16B-aligned, bank-spread

typedef short s8v __attribute__((ext_vector_type(8)));   // 8 bf16 (4 VGPRs)
typedef float f4v __attribute__((ext_vector_type(4)));   // MFMA C/D
typedef unsigned int uint;

__device__ __forceinline__ float rcp_f(float x) {
#if __has_builtin(__builtin_amdgcn_rcpf)
    return __builtin_amdgcn_rcpf(x);
#else
    return 1.0f / x;
#endif
}
__device__ __forceinline__ float tanh_f(float x) {
    float e = __expf(2.0f * x);
    return 1.0f - 2.0f * rcp_f(e + 1.0f);
}
__device__ __forceinline__ float sig_f(float x) {
    return rcp_f(1.0f + __expf(-x));
}
__device__ __forceinline__ uint f2bf(float f) {   // fp32 -> bf16 bits, RNE
    uint u = __float_as_uint(f);
    return (u + 0x7FFFu + ((u >> 16) & 1u)) >> 16;
}
__device__ __forceinline__ s8v pack4(uint a, uint b, uint c, uint d_) {
    union { uint u[4]; s8v v; } x;
    x.u[0] = a; x.u[1] = b; x.u[2] = c; x.u[3] = d_;
    return x.v;
}

// Block = (d, 16-row tile): grid 32*8 = 256 (1/CU), 256 thr (4 waves).
// r14 structure (hi/lo split bf16 MFMA, 3 terms, fp32 C — absmax-exact) with
// the M dimension FULLY USED: all 16 C rows are real batch rows, so the
// garbage half of r14's MFMA output and stage-3 VALU (quads 2-3) is gone.
// Wave wv owns n in [16wv,16wv+16): all 4 gate C-tiles -> lane-local combine.
// Lane (quad,col): C rows quad*4+reg, n = wv*16+col. 2 barriers/step.
__global__ void __launch_bounds__(256, 1)
imv_lstm_scan(const float* __restrict__ x,
              const float* __restrict__ Uj, const float* __restrict__ Ui,
              const float* __restrict__ Uf, const float* __restrict__ Uo,
              const float* __restrict__ Wj, const float* __restrict__ Wi,
              const float* __restrict__ Wf, const float* __restrict__ Wo,
              const float* __restrict__ bj, const float* __restrict__ bi_,
              const float* __restrict__ bf_, const float* __restrict__ bo,
              const float* __restrict__ Fa, const float* __restrict__ Fab,
              const float* __restrict__ Fbw, const float* __restrict__ Fbb,
              const float* __restrict__ Pw, const float* __restrict__ Pb,
              float* __restrict__ wmu, float* __restrict__ wbeta)
{
    __shared__ float sXT[T_LEN][R_TILE];     // 32 KB, [t][r]
    __shared__ uint  sH32[16][HSTRIDE];      // 4.3 KB, h packed hi|lo
    __shared__ float sPS[16][4];             // alpha partials [row][wave]
    __shared__ float sPV[16][4];             // epilogue second buffer

    const int tid  = threadIdx.x;
    const int lane = tid & 63;
    const int wv   = tid >> 6;               // 0..3
    const int quad = lane >> 4;              // 0..3
    const int col  = lane & 15;
    const int d    = blockIdx.x & 31;
    const int rt   = blockIdx.x >> 5;        // 0..7
    const int r0   = rt * R_TILE;
    const int n    = wv * 16 + col;          // this lane's n
    const int row4 = quad * 4;               // this lane's first C row

    // ---- stage x transposed: sXT[t][r] ----
    for (int i = tid; i < R_TILE * T_LEN; i += 256) {
        int t = i >> 4, r = i & 15;
        sXT[t][r] = x[((size_t)(r0 + r) * T_LEN + t) * D_DIM + d];
    }
    for (int i = tid; i < 16 * HSTRIDE; i += 256)
        ((uint*)sH32)[i] = 0u;               // h0 = 0

    // ---- W fragments into registers: Bh/Bl[gate][k-chunk] ----
    s8v Bh[4][2], Bl[4][2];
    #pragma unroll
    for (int g = 0; g < 4; ++g) {
        const float* Wg = (g == 0 ? Wj : g == 1 ? Wi : g == 2 ? Wf : Wo)
                          + d * (N_DIM * N_DIM);
        #pragma unroll
        for (int c = 0; c < 2; ++c) {
            uint hp[4], lp[4];
            #pragma unroll
            for (int jp = 0; jp < 4; ++jp) {
                float w0 = Wg[(32 * c + quad * 8 + 2 * jp + 0) * N_DIM + n];
                float w1 = Wg[(32 * c + quad * 8 + 2 * jp + 1) * N_DIM + n];
                uint u0 = __float_as_uint(w0), u1 = __float_as_uint(w1);
                uint h0b = u0 & 0xFFFF0000u, h1b = u1 & 0xFFFF0000u;
                float l0 = w0 - __uint_as_float(h0b);
                float l1 = w1 - __uint_as_float(h1b);
                hp[jp] = (u0 >> 16) | h1b;
                lp[jp] = f2bf(l0) | (f2bf(l1) << 16);
            }
            Bh[g][c] = pack4(hp[0], hp[1], hp[2], hp[3]);
            Bl[g][c] = pack4(lp[0], lp[1], lp[2], lp[3]);
        }
    }

    const int dn = d * N_DIM + n;
    const float u_j = Uj[dn], u_i = Ui[dn], u_f = Uf[dn], u_o = Uo[dn];
    const float cbj = bj[dn], cbi = bi_[dn], cbf = bf_[dn], cbo = bo[dn];
    const float fan = Fa[dn];
    const float fab = Fab[d];

    __syncthreads();

    float c_[4] = {0.f, 0.f, 0.f, 0.f};
    float h_[4] = {0.f, 0.f, 0.f, 0.f};
    float ga[4] = {0.f, 0.f, 0.f, 0.f};
    float as[4] = {0.f, 0.f, 0.f, 0.f};

    #pragma unroll 1
    for (int t = 0; t < T_LEN; ++t) {
        // ---- A fragments from packed h (hi|lo in each u32) ----
        s8v Ah[2], Al[2];
        #pragma unroll
        for (int c = 0; c < 2; ++c) {
            const uint* hp = &sH32[col][32 * c + quad * 8];
            uint4 wa = *(const uint4*)hp;
            uint4 wb = *(const uint4*)(hp + 4);
            Ah[c] = pack4((wa.x >> 16) | (wa.y & 0xFFFF0000u),
                          (wa.z >> 16) | (wa.w & 0xFFFF0000u),
                          (wb.x >> 16) | (wb.y & 0xFFFF0000u),
                          (wb.z >> 16) | (wb.w & 0xFFFF0000u));
            Al[c] = pack4((wa.x & 0xFFFFu) | (wa.y << 16),
                          (wa.z & 0xFFFFu) | (wa.w << 16),
                          (wb.x & 0xFFFFu) | (wb.y << 16),
                          (wb.z & 0xFFFFu) | (wb.w << 16));
        }

        // ---- 24 MFMAs: 4 gates x 2 k-chunks x 3 hi/lo terms ----
        f4v acc[4];
        #pragma unroll
        for (int g = 0; g < 4; ++g) {
            f4v a = {0.f, 0.f, 0.f, 0.f};
            #pragma unroll
            for (int c = 0; c < 2; ++c) {
                a = __builtin_amdgcn_mfma_f32_16x16x32_bf16(Ah[c], Bh[g][c], a, 0, 0, 0);
                a = __builtin_amdgcn_mfma_f32_16x16x32_bf16(Al[c], Bh[g][c], a, 0, 0, 0);
                a = __builtin_amdgcn_mfma_f32_16x16x32_bf16(Ah[c], Bl[g][c], a, 0, 0, 0);
            }
            acc[g] = a;
        }

        // ---- stage 3: rows row4..row4+3 at n (ALL rows real) ----
        f4v xr = *(const f4v*)&sXT[t][row4];
        float ps[4];
        #pragma unroll
        for (int reg = 0; reg < 4; ++reg) {
            float xv = xr[reg];
            float jp = acc[0][reg] + fmaf(xv, u_j, cbj);
            float ip = acc[1][reg] + fmaf(xv, u_i, cbi);
            float fp = acc[2][reg] + fmaf(xv, u_f, cbf);
            float op = acc[3][reg] + fmaf(xv, u_o, cbo);
            c_[reg] = fmaf(c_[reg], sig_f(fp), sig_f(ip) * tanh_f(jp));
            h_[reg] = sig_f(op) * tanh_f(c_[reg]);
            ps[reg] = h_[reg] * fan;
        }
        // reduce ps over this wave's 16 n (stays within quad-group)
        #pragma unroll
        for (int reg = 0; reg < 4; ++reg) {
            ps[reg] += __shfl_xor(ps[reg], 1);
            ps[reg] += __shfl_xor(ps[reg], 2);
            ps[reg] += __shfl_xor(ps[reg], 4);
            ps[reg] += __shfl_xor(ps[reg], 8);
        }

        __syncthreads();   // B1: all A/sPS reads done before overwrite

        #pragma unroll
        for (int reg = 0; reg < 4; ++reg) {
            float hv = h_[reg];
            uint hb = __float_as_uint(hv) & 0xFFFF0000u;
            float lo = hv - __uint_as_float(hb);
            sH32[row4 + reg][n] = hb | f2bf(lo);
        }
        if (col == 0) {
            #pragma unroll
            for (int reg = 0; reg < 4; ++reg)
                sPS[row4 + reg][wv] = ps[reg];
        }

        __syncthreads();   // B2: h_t and alpha partials visible

        #pragma unroll
        for (int reg = 0; reg < 4; ++reg) {
            f4v tv = *(const f4v*)&sPS[row4 + reg][0];
            float tot = tv[0] + tv[1] + tv[2] + tv[3];
            float al = __expf(tanh_f(tot + fab));
            as[reg] += al;
            ga[reg] = fmaf(al, h_[reg], ga[reg]);
        }
    }

    // ---- epilogue: mu, beta per (row, d) ----
    const float pwa = Pw[n],  pwb = Pw[64 + n];
    const float fwa = Fbw[n], fwb = Fbw[64 + n];
    float pm[4], pv[4];
    #pragma unroll
    for (int reg = 0; reg < 4; ++reg) {
        float gn = ga[reg] * rcp_f(as[reg]);
        pm[reg] = fmaf(gn, pwa, h_[reg] * pwb);
        pv[reg] = fmaf(gn, fwa, h_[reg] * fwb);
        pm[reg] += __shfl_xor(pm[reg], 1); pm[reg] += __shfl_xor(pm[reg], 2);
        pm[reg] += __shfl_xor(pm[reg], 4); pm[reg] += __shfl_xor(pm[reg], 8);
        pv[reg] += __shfl_xor(pv[reg], 1); pv[reg] += __shfl_xor(pv[reg], 2);
        pv[reg] += __shfl_xor(pv[reg], 4); pv[reg] += __shfl_xor(pv[reg], 8);
    }
    __syncthreads();   // in-loop sPS reads done
    if (col == 0) {
        #pragma unroll
        for (int reg = 0; reg < 4; ++reg) {
            sPS[row4 + reg][wv] = pm[reg];
            sPV[row4 + reg][wv] = pv[reg];
        }
    }
    __syncthreads();
    if (tid < R_TILE) {
        int r = tid;
        f4v a = *(const f4v*)&sPS[r][0];
        f4v b2 = *(const f4v*)&sPV[r][0];
        float mu = a[0] + a[1] + a[2] + a[3] + Pb[0];
        float bt = __expf(tanh_f(b2[0] + b2[1] + b2[2] + b2[3] + Fbb[0]));
        wmu  [(r0 + r) * D_DIM + d] = mu;
        wbeta[(r0 + r) * D_DIM + d] = bt;
    }
}

// beta softmax over d + weighted sum -> out[b]
__global__ void imv_finalize(const float* __restrict__ wmu,
                             const float* __restrict__ wbeta,
                             float* __restrict__ out)
{
    int b = blockIdx.x * 64 + threadIdx.x;
    if (b >= B_ALL) return;
    float s1 = 0.f, s2 = 0.f;
    for (int d = 0; d < D_DIM; ++d) {
        float be = wbeta[b * D_DIM + d];
        s1 = fmaf(be, wmu[b * D_DIM + d], s1);
        s2 += be;
    }
    out[b] = s1 / s2;
}

extern "C" void kernel_launch(void* const* d_in, const int* in_sizes, int n_in,
                              void* d_out, int out_size, void* d_ws, size_t ws_size,
                              hipStream_t stream)
{
    const float* x   = (const float*)d_in[0];
    const float* U_j = (const float*)d_in[1];
    const float* U_i = (const float*)d_in[2];
    const float* U_f = (const float*)d_in[3];
    const float* U_o = (const float*)d_in[4];
    const float* W_j = (const float*)d_in[5];
    const float* W_i = (const float*)d_in[6];
    const float* W_f = (const float*)d_in[7];
    const float* W_o = (const float*)d_in[8];
    const float* b_j = (const float*)d_in[9];
    const float* b_i = (const float*)d_in[10];
    const float* b_f = (const float*)d_in[11];
    const float* b_o = (const float*)d_in[12];
    const float* Fan  = (const float*)d_in[13];
    const float* Fanb = (const float*)d_in[14];
    const float* Fbw  = (const float*)d_in[15];
    const float* Fbb  = (const float*)d_in[16];
    const float* Phw  = (const float*)d_in[17];
    const float* Phb  = (const float*)d_in[18];

    float* wmu   = (float*)d_ws;
    float* wbeta = wmu + B_ALL * D_DIM;

    imv_lstm_scan<<<dim3(256), dim3(256), 0, stream>>>(
        x, U_j, U_i, U_f, U_o, W_j, W_i, W_f, W_o,
        b_j, b_i, b_f, b_o, Fan, Fanb, Fbw, Fbb, Phw, Phb,
        wmu, wbeta);

    imv_finalize<<<dim3(2), dim3(64), 0, stream>>>(wmu, wbeta, (float*)d_out);
}